// Round 1
// baseline (3352.610 us; speedup 1.0000x reference)
//
#include <hip/hip_runtime.h>

#define HID 256
#define TLEN 1024
#define BATCH 128

typedef _Float16 half2_t __attribute__((ext_vector_type(2)));

__device__ __forceinline__ float fexp2(float x) { return __builtin_amdgcn_exp2f(x); }
__device__ __forceinline__ float frcp(float x)  { return __builtin_amdgcn_rcpf(x); }
// sigmoid(x) = 1/(1+2^(-x*log2e))
__device__ __forceinline__ float fast_sigmoid(float x) {
  return frcp(1.0f + fexp2(-1.442695040888963f * x));
}
// tanh(x) = 1 - 2/(2^(2x*log2e)+1)
__device__ __forceinline__ float fast_tanh(float x) {
  float e = fexp2(2.885390081777927f * x);
  return 1.0f - 2.0f * frcp(e + 1.0f);
}

#if defined(__has_builtin)
#if __has_builtin(__builtin_amdgcn_fdot2)
#define HAVE_FDOT2 1
#endif
#endif

__device__ __forceinline__ float dot2acc(half2_t a, half2_t b, float c) {
#ifdef HAVE_FDOT2
  return __builtin_amdgcn_fdot2(a, b, c, false);   // v_dot2_f32_f16
#else
  return c + (float)a.x * (float)b.x + (float)a.y * (float)b.y;
#endif
}

// One block per batch element. 256 threads; thread t owns W_hh rows
// {t, 256+t, 512+t} (r,z,n for hidden dim t) as f16 pairs in VGPRs
// (3*128 = 384 VGPRs; __launch_bounds__(256,1) -> 1 wave/SIMD, 512-reg budget).
// h broadcast each step via LDS (f16, double-buffered); h_old fp32 stays in a
// register per thread. One barrier per step.
__global__ __launch_bounds__(256, 1)
void momgru_persistent(const float* __restrict__ x,
                       const float* __restrict__ W_ih,
                       const float* __restrict__ W_hh,
                       const float* __restrict__ b_ih,
                       const float* __restrict__ b_hh,
                       const float* __restrict__ Wb_x,
                       const float* __restrict__ Wb_h,
                       const float* __restrict__ b_beta,
                       const float* __restrict__ s_ptr,
                       const float* __restrict__ W_head,
                       const float* __restrict__ b_head,
                       float* __restrict__ out)  // [0,128) = head out, [128, 128+B*T) = betas
{
  const int b    = blockIdx.x;
  const int tid  = threadIdx.x;
  const int lane = tid & 63;
  const int wv   = tid >> 6;

  __shared__ float   x_sh[TLEN * 2];        // 8 KB: this sequence's inputs
  __shared__ half2_t hbuf[2][HID / 2];      // double-buffered f16 hidden state
  __shared__ float   red[2][4];             // per-wave partials for beta dot

  // ---- stage x for this sequence (coalesced) ----
  const float* xb = x + (size_t)b * TLEN * 2;
  for (int i = tid; i < TLEN * 2; i += 256) x_sh[i] = xb[i];

  // ---- load recurrent weights into registers as f16 pairs ----
  half2_t wr[128], wz[128], wn[128];
  {
    const float4* rowr = reinterpret_cast<const float4*>(W_hh + (size_t)(0 * HID + tid) * HID);
    const float4* rowz = reinterpret_cast<const float4*>(W_hh + (size_t)(1 * HID + tid) * HID);
    const float4* rown = reinterpret_cast<const float4*>(W_hh + (size_t)(2 * HID + tid) * HID);
#pragma unroll
    for (int k = 0; k < 64; ++k) {
      float4 f = rowr[k];
      wr[2 * k]     = half2_t{(_Float16)f.x, (_Float16)f.y};
      wr[2 * k + 1] = half2_t{(_Float16)f.z, (_Float16)f.w};
    }
#pragma unroll
    for (int k = 0; k < 64; ++k) {
      float4 f = rowz[k];
      wz[2 * k]     = half2_t{(_Float16)f.x, (_Float16)f.y};
      wz[2 * k + 1] = half2_t{(_Float16)f.z, (_Float16)f.w};
    }
#pragma unroll
    for (int k = 0; k < 64; ++k) {
      float4 f = rown[k];
      wn[2 * k]     = half2_t{(_Float16)f.x, (_Float16)f.y};
      wn[2 * k + 1] = half2_t{(_Float16)f.z, (_Float16)f.w};
    }
  }

  // ---- per-thread constants ----
  const float bih_r = b_ih[tid], bih_z = b_ih[HID + tid], bih_n = b_ih[2 * HID + tid];
  const float bhh_r = b_hh[tid], bhh_z = b_hh[HID + tid], bhh_n = b_hh[2 * HID + tid];
  const float wih_r0 = W_ih[2 * tid],             wih_r1 = W_ih[2 * tid + 1];
  const float wih_z0 = W_ih[2 * (HID + tid)],     wih_z1 = W_ih[2 * (HID + tid) + 1];
  const float wih_n0 = W_ih[2 * (2 * HID + tid)], wih_n1 = W_ih[2 * (2 * HID + tid) + 1];
  const float wbx0 = Wb_x[0], wbx1 = Wb_x[1];
  const float bbeta = b_beta[0], sv = s_ptr[0];
  const float wbh_t = Wb_h[tid];
  const float whead_t = W_head[tid];

  // ---- init state ----
  if (tid < HID / 2) {
    hbuf[0][tid] = half2_t{(_Float16)0.0f, (_Float16)0.0f};
    hbuf[1][tid] = half2_t{(_Float16)0.0f, (_Float16)0.0f};
  }
  float h_old = 0.0f, vr = 0.0f, vz = 0.0f, vn = 0.0f;
  float hWb = 0.0f;  // h_{t-1} . Wb_h, carried across steps
  float* betas = out + BATCH;
  __syncthreads();

  int cur = 0;
  for (int t = 0; t < TLEN; ++t) {
    const float x0 = x_sh[2 * t], x1 = x_sh[2 * t + 1];
    const float beta = fast_sigmoid(x0 * wbx0 + x1 * wbx1 + hWb + bbeta);

    vr = beta * vr + sv * (wih_r0 * x0 + wih_r1 * x1 + bih_r);
    vz = beta * vz + sv * (wih_z0 * x0 + wih_z1 * x1 + bih_z);
    vn = beta * vn + sv * (wih_n0 * x0 + wih_n1 * x1 + bih_n);

    // gh dots: 3 gates x 128 dot2, h broadcast from LDS as float4 (=4 half2)
    float ar0 = bhh_r, az0 = bhh_z, an0 = bhh_n;
    float ar1 = 0.0f, az1 = 0.0f, an1 = 0.0f;
    const float4* h4 = reinterpret_cast<const float4*>(hbuf[cur]);
#pragma unroll
    for (int k = 0; k < 32; ++k) {
      float4 f = h4[k];
      half2_t ha = __builtin_bit_cast(half2_t, f.x);
      half2_t hb = __builtin_bit_cast(half2_t, f.y);
      half2_t hc = __builtin_bit_cast(half2_t, f.z);
      half2_t hd = __builtin_bit_cast(half2_t, f.w);
      ar0 = dot2acc(wr[4 * k + 0], ha, ar0);
      az0 = dot2acc(wz[4 * k + 0], ha, az0);
      an0 = dot2acc(wn[4 * k + 0], ha, an0);
      ar1 = dot2acc(wr[4 * k + 1], hb, ar1);
      az1 = dot2acc(wz[4 * k + 1], hb, az1);
      an1 = dot2acc(wn[4 * k + 1], hb, an1);
      ar0 = dot2acc(wr[4 * k + 2], hc, ar0);
      az0 = dot2acc(wz[4 * k + 2], hc, az0);
      an0 = dot2acc(wn[4 * k + 2], hc, an0);
      ar1 = dot2acc(wr[4 * k + 3], hd, ar1);
      az1 = dot2acc(wz[4 * k + 3], hd, az1);
      an1 = dot2acc(wn[4 * k + 3], hd, an1);
    }
    const float gr = ar0 + ar1;
    const float gz = az0 + az1;
    const float gn = an0 + an1;

    const float r = fast_sigmoid(vr + gr);
    const float z = fast_sigmoid(vz + gz);
    const float n = fast_tanh(vn + r * gn);
    h_old = (1.0f - z) * n + z * h_old;

    const int nxt = cur ^ 1;
    reinterpret_cast<_Float16*>(hbuf[nxt])[tid] = (_Float16)h_old;

    // beta dot partial: reduce h_new . Wb_h across the block
    float p = h_old * wbh_t;
#pragma unroll
    for (int off = 32; off; off >>= 1) p += __shfl_xor(p, off, 64);
    const int rb = t & 1;
    if (lane == 0) red[rb][wv] = p;
    if (tid == 0) betas[(size_t)b * TLEN + t] = beta;
    __syncthreads();
    hWb = red[rb][0] + red[rb][1] + red[rb][2] + red[rb][3];
    cur = nxt;
  }

  // ---- head: out[b] = h_T . W_head + b_head ----
  float p = h_old * whead_t;
#pragma unroll
  for (int off = 32; off; off >>= 1) p += __shfl_xor(p, off, 64);
  if (lane == 0) red[0][wv] = p;
  __syncthreads();
  if (tid == 0) out[b] = red[0][0] + red[0][1] + red[0][2] + red[0][3] + b_head[0];
}

extern "C" void kernel_launch(void* const* d_in, const int* in_sizes, int n_in,
                              void* d_out, int out_size, void* d_ws, size_t ws_size,
                              hipStream_t stream) {
  const float* x      = (const float*)d_in[0];
  const float* W_ih   = (const float*)d_in[1];
  const float* W_hh   = (const float*)d_in[2];
  const float* b_ih   = (const float*)d_in[3];
  const float* b_hh   = (const float*)d_in[4];
  const float* Wb_x   = (const float*)d_in[5];
  const float* Wb_h   = (const float*)d_in[6];
  const float* b_beta = (const float*)d_in[7];
  const float* s      = (const float*)d_in[8];
  const float* W_head = (const float*)d_in[9];
  const float* b_head = (const float*)d_in[10];
  float* out = (float*)d_out;

  momgru_persistent<<<dim3(BATCH), dim3(256), 0, stream>>>(
      x, W_ih, W_hh, b_ih, b_hh, Wb_x, Wb_h, b_beta, s, W_head, b_head, out);
}

// Round 2
// 1473.091 us; speedup vs baseline: 2.2759x; 2.2759x over previous
//
#include <hip/hip_runtime.h>

#define HID 256
#define TLEN 1024
#define BATCH 128

typedef _Float16 half2_t __attribute__((ext_vector_type(2)));

__device__ __forceinline__ float fexp2(float x) { return __builtin_amdgcn_exp2f(x); }
__device__ __forceinline__ float frcp(float x)  { return __builtin_amdgcn_rcpf(x); }
// sigmoid(x) = 1/(1+2^(-x*log2e))
__device__ __forceinline__ float fast_sigmoid(float x) {
  return frcp(1.0f + fexp2(-1.442695040888963f * x));
}
// tanh(x) = 1 - 2/(2^(2x*log2e)+1)
__device__ __forceinline__ float fast_tanh(float x) {
  float e = fexp2(2.885390081777927f * x);
  return 1.0f - 2.0f * frcp(e + 1.0f);
}

#if defined(__has_builtin)
#if __has_builtin(__builtin_amdgcn_fdot2)
#define HAVE_FDOT2 1
#endif
#endif

__device__ __forceinline__ float dot2acc(half2_t a, half2_t b, float c) {
#ifdef HAVE_FDOT2
  return __builtin_amdgcn_fdot2(a, b, c, false);   // v_dot2_f32_f16
#else
  return c + (float)a.x * (float)b.x + (float)a.y * (float)b.y;
#endif
}

// One block per batch element, 512 threads (8 waves, 2 waves/SIMD).
// Thread (d = tid>>1, half = tid&1) owns the k-range [half*128, half*128+128)
// of W_hh rows {d, 256+d, 512+d} as f16 pairs: 3 * 64 = 192 half2 VGPRs.
// This fits the 256 arch-VGPR cap (round-1's 384-reg layout spilled to
// scratch: WRITE_SIZE showed the 50 MB spill store). Pair partials combine
// via __shfl_xor(,1); h broadcast per step via f16 LDS (double-buffered).
__global__ __launch_bounds__(512, 1)
void momgru_persistent(const float* __restrict__ x,
                       const float* __restrict__ W_ih,
                       const float* __restrict__ W_hh,
                       const float* __restrict__ b_ih,
                       const float* __restrict__ b_hh,
                       const float* __restrict__ Wb_x,
                       const float* __restrict__ Wb_h,
                       const float* __restrict__ b_beta,
                       const float* __restrict__ s_ptr,
                       const float* __restrict__ W_head,
                       const float* __restrict__ b_head,
                       float* __restrict__ out)  // [0,128) head, [128,128+B*T) betas
{
  const int b    = blockIdx.x;
  const int tid  = threadIdx.x;
  const int lane = tid & 63;
  const int wv   = tid >> 6;     // 0..7
  const int d    = tid >> 1;     // hidden dim 0..255
  const int half = tid & 1;      // k-chunk selector

  __shared__ float   x_sh[TLEN * 2];      // 8 KB
  __shared__ half2_t hbuf[2][HID / 2];    // 1 KB, double-buffered f16 h
  __shared__ float   red[2][8];           // per-wave partials

  // ---- stage x (coalesced) ----
  const float* xb = x + (size_t)b * TLEN * 2;
  for (int i = tid; i < TLEN * 2; i += 512) x_sh[i] = xb[i];

  // ---- load this thread's weight slice into registers as f16 pairs ----
  half2_t wr[64], wz[64], wn[64];
  {
    const float4* rowr = reinterpret_cast<const float4*>(W_hh + (size_t)(0 * HID + d) * HID + half * 128);
    const float4* rowz = reinterpret_cast<const float4*>(W_hh + (size_t)(1 * HID + d) * HID + half * 128);
    const float4* rown = reinterpret_cast<const float4*>(W_hh + (size_t)(2 * HID + d) * HID + half * 128);
#pragma unroll
    for (int k = 0; k < 32; ++k) {
      float4 f = rowr[k];
      wr[2 * k]     = half2_t{(_Float16)f.x, (_Float16)f.y};
      wr[2 * k + 1] = half2_t{(_Float16)f.z, (_Float16)f.w};
    }
#pragma unroll
    for (int k = 0; k < 32; ++k) {
      float4 f = rowz[k];
      wz[2 * k]     = half2_t{(_Float16)f.x, (_Float16)f.y};
      wz[2 * k + 1] = half2_t{(_Float16)f.z, (_Float16)f.w};
    }
#pragma unroll
    for (int k = 0; k < 32; ++k) {
      float4 f = rown[k];
      wn[2 * k]     = half2_t{(_Float16)f.x, (_Float16)f.y};
      wn[2 * k + 1] = half2_t{(_Float16)f.z, (_Float16)f.w};
    }
  }

  // ---- per-thread constants (indexed by d; pair threads load same values) ----
  const float bih_r = b_ih[d], bih_z = b_ih[HID + d], bih_n = b_ih[2 * HID + d];
  const float bhh_r = b_hh[d], bhh_z = b_hh[HID + d], bhh_n = b_hh[2 * HID + d];
  const float wih_r0 = W_ih[2 * d],             wih_r1 = W_ih[2 * d + 1];
  const float wih_z0 = W_ih[2 * (HID + d)],     wih_z1 = W_ih[2 * (HID + d) + 1];
  const float wih_n0 = W_ih[2 * (2 * HID + d)], wih_n1 = W_ih[2 * (2 * HID + d) + 1];
  const float wbx0 = Wb_x[0], wbx1 = Wb_x[1];
  const float bbeta = b_beta[0], sv = s_ptr[0];
  const float wbh_t = Wb_h[d];
  const float whead_t = W_head[d];

  // ---- init state ----
  if (tid < HID / 2) {
    hbuf[0][tid] = half2_t{(_Float16)0.0f, (_Float16)0.0f};
    hbuf[1][tid] = half2_t{(_Float16)0.0f, (_Float16)0.0f};
  }
  float h_old = 0.0f, vr = 0.0f, vz = 0.0f, vn = 0.0f;   // live on even threads
  float hWb = 0.0f;
  float* betas = out + BATCH;
  __syncthreads();

  int cur = 0;
  for (int t = 0; t < TLEN; ++t) {
    const float x0 = x_sh[2 * t], x1 = x_sh[2 * t + 1];
    const float beta = fast_sigmoid(x0 * wbx0 + x1 * wbx1 + hWb + bbeta);

    // momentum update (state meaningful on even threads only)
    vr = beta * vr + sv * (wih_r0 * x0 + wih_r1 * x1 + bih_r);
    vz = beta * vz + sv * (wih_z0 * x0 + wih_z1 * x1 + bih_z);
    vn = beta * vn + sv * (wih_n0 * x0 + wih_n1 * x1 + bih_n);

    // gh partial dots over this thread's 128-element k-chunk
    float ar0 = 0.0f, az0 = 0.0f, an0 = 0.0f;
    float ar1 = 0.0f, az1 = 0.0f, an1 = 0.0f;
    const float4* h4 = reinterpret_cast<const float4*>(&hbuf[cur][half * 64]);
#pragma unroll
    for (int k = 0; k < 16; ++k) {
      float4 f = h4[k];
      half2_t ha = __builtin_bit_cast(half2_t, f.x);
      half2_t hb = __builtin_bit_cast(half2_t, f.y);
      half2_t hc = __builtin_bit_cast(half2_t, f.z);
      half2_t hd = __builtin_bit_cast(half2_t, f.w);
      ar0 = dot2acc(wr[4 * k + 0], ha, ar0);
      az0 = dot2acc(wz[4 * k + 0], ha, az0);
      an0 = dot2acc(wn[4 * k + 0], ha, an0);
      ar1 = dot2acc(wr[4 * k + 1], hb, ar1);
      az1 = dot2acc(wz[4 * k + 1], hb, az1);
      an1 = dot2acc(wn[4 * k + 1], hb, an1);
      ar0 = dot2acc(wr[4 * k + 2], hc, ar0);
      az0 = dot2acc(wz[4 * k + 2], hc, az0);
      an0 = dot2acc(wn[4 * k + 2], hc, an0);
      ar1 = dot2acc(wr[4 * k + 3], hd, ar1);
      az1 = dot2acc(wz[4 * k + 3], hd, az1);
      an1 = dot2acc(wn[4 * k + 3], hd, an1);
    }
    // combine pair partials (lane xor 1)
    float gr = ar0 + ar1;
    float gz = az0 + az1;
    float gn = an0 + an1;
    gr += __shfl_xor(gr, 1, 64);
    gz += __shfl_xor(gz, 1, 64);
    gn += __shfl_xor(gn, 1, 64);

    float p = 0.0f;
    if (half == 0) {
      const float r = fast_sigmoid(vr + gr + bhh_r);
      const float z = fast_sigmoid(vz + gz + bhh_z);
      const float n = fast_tanh(vn + (gn + bhh_n) * r);
      h_old = (1.0f - z) * n + z * h_old;
      reinterpret_cast<_Float16*>(hbuf[cur ^ 1])[d] = (_Float16)h_old;
      p = h_old * wbh_t;
    }
    // block-reduce p -> next step's hWb
#pragma unroll
    for (int off = 32; off; off >>= 1) p += __shfl_xor(p, off, 64);
    const int rb = t & 1;
    if (lane == 0) red[rb][wv] = p;
    if (tid == 0) betas[(size_t)b * TLEN + t] = beta;
    __syncthreads();
    hWb = red[rb][0] + red[rb][1] + red[rb][2] + red[rb][3] +
          red[rb][4] + red[rb][5] + red[rb][6] + red[rb][7];
    cur ^= 1;
  }

  // ---- head: out[b] = h_T . W_head + b_head ----
  float p = (half == 0) ? h_old * whead_t : 0.0f;
#pragma unroll
  for (int off = 32; off; off >>= 1) p += __shfl_xor(p, off, 64);
  if (lane == 0) red[0][wv] = p;     // last loop iter used red[1]; no race
  __syncthreads();
  if (tid == 0) {
    out[b] = red[0][0] + red[0][1] + red[0][2] + red[0][3] +
             red[0][4] + red[0][5] + red[0][6] + red[0][7] + b_head[0];
  }
}

extern "C" void kernel_launch(void* const* d_in, const int* in_sizes, int n_in,
                              void* d_out, int out_size, void* d_ws, size_t ws_size,
                              hipStream_t stream) {
  const float* x      = (const float*)d_in[0];
  const float* W_ih   = (const float*)d_in[1];
  const float* W_hh   = (const float*)d_in[2];
  const float* b_ih   = (const float*)d_in[3];
  const float* b_hh   = (const float*)d_in[4];
  const float* Wb_x   = (const float*)d_in[5];
  const float* Wb_h   = (const float*)d_in[6];
  const float* b_beta = (const float*)d_in[7];
  const float* s      = (const float*)d_in[8];
  const float* W_head = (const float*)d_in[9];
  const float* b_head = (const float*)d_in[10];
  float* out = (float*)d_out;

  momgru_persistent<<<dim3(BATCH), dim3(512), 0, stream>>>(
      x, W_ih, W_hh, b_ih, b_hh, Wb_x, Wb_h, b_beta, s, W_head, b_head, out);
}

// Round 3
// 1469.521 us; speedup vs baseline: 2.2814x; 1.0024x over previous
//
#include <hip/hip_runtime.h>

#define HID 256
#define TLEN 1024
#define BATCH 128

typedef _Float16 half2_t __attribute__((ext_vector_type(2)));

__device__ __forceinline__ float fexp2(float x) { return __builtin_amdgcn_exp2f(x); }
__device__ __forceinline__ float frcp(float x)  { return __builtin_amdgcn_rcpf(x); }
// sigmoid(x) = 1/(1+2^(-x*log2e))
__device__ __forceinline__ float fast_sigmoid(float x) {
  return frcp(1.0f + fexp2(-1.442695040888963f * x));
}
// tanh(x) = 1 - 2/(2^(2x*log2e)+1)
__device__ __forceinline__ float fast_tanh(float x) {
  float e = fexp2(2.885390081777927f * x);
  return 1.0f - 2.0f * frcp(e + 1.0f);
}

#if defined(__has_builtin)
#if __has_builtin(__builtin_amdgcn_fdot2)
#define HAVE_FDOT2 1
#endif
#endif

__device__ __forceinline__ float dot2acc(half2_t a, half2_t b, float c) {
#ifdef HAVE_FDOT2
  return __builtin_amdgcn_fdot2(a, b, c, false);   // v_dot2_f32_f16
#else
  return c + (float)a.x * (float)b.x + (float)a.y * (float)b.y;
#endif
}

// One block per batch element, 512 threads (8 waves, 2 waves/SIMD).
// Thread (d = tid>>1, half = tid&1) owns half the k-range of W_hh rows
// {d, 256+d, 512+d} as f16 pairs: 3 * 64 = 192 half2 VGPRs (+~40 temps).
// amdgpu_waves_per_eu(2,2) pins the allocator to the 256-VGPR/wave budget
// (round 2: launch_bounds(512,1) let it clamp to 128 and spill 50 MB of
// weights to scratch — WRITE_SIZE was the tell).
// The k-split is INTERLEAVED by 16-byte h-blocks: half=0 reads even 16-B
// blocks of hbuf, half=1 odd blocks -> even/odd lanes hit disjoint bank
// quads (round 2's 128-B-apart split caused 6.7e7 conflict cycles).
__global__
__attribute__((amdgpu_flat_work_group_size(512, 512)))
__attribute__((amdgpu_waves_per_eu(2, 2)))
void momgru_persistent(const float* __restrict__ x,
                       const float* __restrict__ W_ih,
                       const float* __restrict__ W_hh,
                       const float* __restrict__ b_ih,
                       const float* __restrict__ b_hh,
                       const float* __restrict__ Wb_x,
                       const float* __restrict__ Wb_h,
                       const float* __restrict__ b_beta,
                       const float* __restrict__ s_ptr,
                       const float* __restrict__ W_head,
                       const float* __restrict__ b_head,
                       float* __restrict__ out)  // [0,128) head, [128,128+B*T) betas
{
  const int b    = blockIdx.x;
  const int tid  = threadIdx.x;
  const int lane = tid & 63;
  const int wv   = tid >> 6;     // 0..7
  const int d    = tid >> 1;     // hidden dim 0..255
  const int half = tid & 1;      // k-chunk selector (interleaved 16-B blocks)

  __shared__ float   x_sh[TLEN * 2];      // 8 KB
  __shared__ half2_t hbuf[2][HID / 2];    // 1 KB, double-buffered f16 h
  __shared__ float   red[2][8];           // per-wave partials

  // ---- stage x (coalesced) ----
  const float* xb = x + (size_t)b * TLEN * 2;
  for (int i = tid; i < TLEN * 2; i += 512) x_sh[i] = xb[i];

  // ---- load this thread's weight slice into registers as f16 pairs ----
  // h 16-B block j' = 2j+half covers f16 elements [(2j+half)*8, +8), which is
  // fp32 float4 indices 4j+2*half and 4j+2*half+1 of the 64 float4 per row.
  half2_t wr[64], wz[64], wn[64];
  {
    const float4* rowr = reinterpret_cast<const float4*>(W_hh + (size_t)(0 * HID + d) * HID);
    const float4* rowz = reinterpret_cast<const float4*>(W_hh + (size_t)(1 * HID + d) * HID);
    const float4* rown = reinterpret_cast<const float4*>(W_hh + (size_t)(2 * HID + d) * HID);
#pragma unroll
    for (int j = 0; j < 16; ++j) {
      float4 f0 = rowr[4 * j + 2 * half];
      float4 f1 = rowr[4 * j + 2 * half + 1];
      wr[4 * j + 0] = half2_t{(_Float16)f0.x, (_Float16)f0.y};
      wr[4 * j + 1] = half2_t{(_Float16)f0.z, (_Float16)f0.w};
      wr[4 * j + 2] = half2_t{(_Float16)f1.x, (_Float16)f1.y};
      wr[4 * j + 3] = half2_t{(_Float16)f1.z, (_Float16)f1.w};
    }
#pragma unroll
    for (int j = 0; j < 16; ++j) {
      float4 f0 = rowz[4 * j + 2 * half];
      float4 f1 = rowz[4 * j + 2 * half + 1];
      wz[4 * j + 0] = half2_t{(_Float16)f0.x, (_Float16)f0.y};
      wz[4 * j + 1] = half2_t{(_Float16)f0.z, (_Float16)f0.w};
      wz[4 * j + 2] = half2_t{(_Float16)f1.x, (_Float16)f1.y};
      wz[4 * j + 3] = half2_t{(_Float16)f1.z, (_Float16)f1.w};
    }
#pragma unroll
    for (int j = 0; j < 16; ++j) {
      float4 f0 = rown[4 * j + 2 * half];
      float4 f1 = rown[4 * j + 2 * half + 1];
      wn[4 * j + 0] = half2_t{(_Float16)f0.x, (_Float16)f0.y};
      wn[4 * j + 1] = half2_t{(_Float16)f0.z, (_Float16)f0.w};
      wn[4 * j + 2] = half2_t{(_Float16)f1.x, (_Float16)f1.y};
      wn[4 * j + 3] = half2_t{(_Float16)f1.z, (_Float16)f1.w};
    }
  }

  // ---- per-thread constants (indexed by d; pair threads load same values) ----
  const float bih_r = b_ih[d], bih_z = b_ih[HID + d], bih_n = b_ih[2 * HID + d];
  const float bhh_r = b_hh[d], bhh_z = b_hh[HID + d], bhh_n = b_hh[2 * HID + d];
  const float wih_r0 = W_ih[2 * d],             wih_r1 = W_ih[2 * d + 1];
  const float wih_z0 = W_ih[2 * (HID + d)],     wih_z1 = W_ih[2 * (HID + d) + 1];
  const float wih_n0 = W_ih[2 * (2 * HID + d)], wih_n1 = W_ih[2 * (2 * HID + d) + 1];
  const float wbx0 = Wb_x[0], wbx1 = Wb_x[1];
  const float bbeta = b_beta[0], sv = s_ptr[0];
  const float wbh_t = Wb_h[d];
  const float whead_t = W_head[d];

  // ---- init state ----
  if (tid < HID / 2) {
    hbuf[0][tid] = half2_t{(_Float16)0.0f, (_Float16)0.0f};
    hbuf[1][tid] = half2_t{(_Float16)0.0f, (_Float16)0.0f};
  }
  float h_old = 0.0f, vr = 0.0f, vz = 0.0f, vn = 0.0f;   // live on even threads
  float hWb = 0.0f;
  float* betas = out + BATCH;
  __syncthreads();

  int cur = 0;
  for (int t = 0; t < TLEN; ++t) {
    const float x0 = x_sh[2 * t], x1 = x_sh[2 * t + 1];
    const float beta = fast_sigmoid(x0 * wbx0 + x1 * wbx1 + hWb + bbeta);

    // momentum update (state meaningful on even threads only)
    vr = beta * vr + sv * (wih_r0 * x0 + wih_r1 * x1 + bih_r);
    vz = beta * vz + sv * (wih_z0 * x0 + wih_z1 * x1 + bih_z);
    vn = beta * vn + sv * (wih_n0 * x0 + wih_n1 * x1 + bih_n);

    // gh partial dots over this thread's interleaved 16-B h-blocks
    float ar0 = 0.0f, az0 = 0.0f, an0 = 0.0f;
    float ar1 = 0.0f, az1 = 0.0f, an1 = 0.0f;
    const float4* hb4 = reinterpret_cast<const float4*>(hbuf[cur]);  // 32 x 16B
#pragma unroll
    for (int j = 0; j < 16; ++j) {
      float4 f = hb4[2 * j + half];
      half2_t ha = __builtin_bit_cast(half2_t, f.x);
      half2_t hb = __builtin_bit_cast(half2_t, f.y);
      half2_t hc = __builtin_bit_cast(half2_t, f.z);
      half2_t hd = __builtin_bit_cast(half2_t, f.w);
      ar0 = dot2acc(wr[4 * j + 0], ha, ar0);
      az0 = dot2acc(wz[4 * j + 0], ha, az0);
      an0 = dot2acc(wn[4 * j + 0], ha, an0);
      ar1 = dot2acc(wr[4 * j + 1], hb, ar1);
      az1 = dot2acc(wz[4 * j + 1], hb, az1);
      an1 = dot2acc(wn[4 * j + 1], hb, an1);
      ar0 = dot2acc(wr[4 * j + 2], hc, ar0);
      az0 = dot2acc(wz[4 * j + 2], hc, az0);
      an0 = dot2acc(wn[4 * j + 2], hc, an0);
      ar1 = dot2acc(wr[4 * j + 3], hd, ar1);
      az1 = dot2acc(wz[4 * j + 3], hd, az1);
      an1 = dot2acc(wn[4 * j + 3], hd, an1);
    }
    // combine pair partials (lane xor 1)
    float gr = ar0 + ar1;
    float gz = az0 + az1;
    float gn = an0 + an1;
    gr += __shfl_xor(gr, 1, 64);
    gz += __shfl_xor(gz, 1, 64);
    gn += __shfl_xor(gn, 1, 64);

    float p = 0.0f;
    if (half == 0) {
      const float r = fast_sigmoid(vr + gr + bhh_r);
      const float z = fast_sigmoid(vz + gz + bhh_z);
      const float n = fast_tanh(vn + (gn + bhh_n) * r);
      h_old = (1.0f - z) * n + z * h_old;
      reinterpret_cast<_Float16*>(hbuf[cur ^ 1])[d] = (_Float16)h_old;
      p = h_old * wbh_t;
    }
    // block-reduce p -> next step's hWb
#pragma unroll
    for (int off = 32; off; off >>= 1) p += __shfl_xor(p, off, 64);
    const int rb = t & 1;
    if (lane == 0) red[rb][wv] = p;
    if (tid == 0) betas[(size_t)b * TLEN + t] = beta;
    __syncthreads();
    hWb = red[rb][0] + red[rb][1] + red[rb][2] + red[rb][3] +
          red[rb][4] + red[rb][5] + red[rb][6] + red[rb][7];
    cur ^= 1;
  }

  // ---- head: out[b] = h_T . W_head + b_head ----
  float p = (half == 0) ? h_old * whead_t : 0.0f;
#pragma unroll
  for (int off = 32; off; off >>= 1) p += __shfl_xor(p, off, 64);
  if (lane == 0) red[0][wv] = p;
  __syncthreads();
  if (tid == 0) {
    out[b] = red[0][0] + red[0][1] + red[0][2] + red[0][3] +
             red[0][4] + red[0][5] + red[0][6] + red[0][7] + b_head[0];
  }
}

extern "C" void kernel_launch(void* const* d_in, const int* in_sizes, int n_in,
                              void* d_out, int out_size, void* d_ws, size_t ws_size,
                              hipStream_t stream) {
  const float* x      = (const float*)d_in[0];
  const float* W_ih   = (const float*)d_in[1];
  const float* W_hh   = (const float*)d_in[2];
  const float* b_ih   = (const float*)d_in[3];
  const float* b_hh   = (const float*)d_in[4];
  const float* Wb_x   = (const float*)d_in[5];
  const float* Wb_h   = (const float*)d_in[6];
  const float* b_beta = (const float*)d_in[7];
  const float* s      = (const float*)d_in[8];
  const float* W_head = (const float*)d_in[9];
  const float* b_head = (const float*)d_in[10];
  float* out = (float*)d_out;

  momgru_persistent<<<dim3(BATCH), dim3(512), 0, stream>>>(
      x, W_ih, W_hh, b_ih, b_hh, Wb_x, Wb_h, b_beta, s, W_head, b_head, out);
}